// Round 1
// baseline (66885.596 us; speedup 1.0000x reference)
//
#include <hip/hip_runtime.h>
#include <math.h>

#define GG 512
#define TT 25
#define PP 10
#define MM 5
#define EE 32
#define HID 32
#define HH 128
#define NEDGE 40
#define NGRAPH (GG*TT)          // 12800
#define NTOT (GG*TT*PP)         // 128000

// ---------------------------------------------------------------------------
// Prep: transpose LSTM weights into [t][k][j][gate] (float4 per (k,j)) and
// copy h0/c0 into workspace state buffers.
// ---------------------------------------------------------------------------
__global__ void prep_kernel(const float* __restrict__ W_ih, const float* __restrict__ W_hh,
                            const float* __restrict__ hx0, const float* __restrict__ cx0,
                            float* __restrict__ wtih, float* __restrict__ wthh,
                            float* __restrict__ h, float* __restrict__ c)
{
    const int N1 = 25*66*512;    // 844800
    const int N2 = 25*128*512;   // 1638400
    const int N3 = 5120*128;     // 655360
    const int total = N1 + N2 + 2*N3;
    for (int idx = blockIdx.x*blockDim.x + threadIdx.x; idx < total; idx += gridDim.x*blockDim.x) {
        if (idx < N1) {
            int t = idx / (66*512); int rem = idx % (66*512);
            int k = rem / 512; int jc = rem % 512;
            int j = jc >> 2, q = jc & 3;
            wtih[idx] = W_ih[(t*512 + 128*q + j)*66 + k];
        } else if (idx < N1+N2) {
            int i2 = idx - N1;
            int t = i2 / (128*512); int rem = i2 % (128*512);
            int k = rem / 512; int jc = rem % 512;
            int j = jc >> 2, q = jc & 3;
            wthh[i2] = W_hh[(t*512 + 128*q + j)*128 + k];
        } else if (idx < N1+N2+N3) {
            int i3 = idx - N1 - N2;
            h[i3] = hx0[i3];
        } else {
            int i4 = idx - N1 - N2 - N3;
            c[i4] = cx0[i4];
        }
    }
}

// ---------------------------------------------------------------------------
// Graph kernel: one 64-thread block per (g,t) vote graph. Computes base signed
// SAGE layer + 2 deep layers entirely in LDS, writes [hp|hn] (64 f32/node).
// Lane roles for GEMMs: sign = lane>>5, g4 = (lane>>3)&3 (k-partition),
// l8 = lane&7 (4-col quad). acc[10 nodes][4 cols] per lane.
// ---------------------------------------------------------------------------
__global__ __launch_bounds__(64) void graph_kernel(
    const float* __restrict__ x0,
    const float* __restrict__ Wb_pos, const float* __restrict__ bb_pos,
    const float* __restrict__ Wb_neg, const float* __restrict__ bb_neg,
    const float* __restrict__ Wd_pos, const float* __restrict__ bd_pos,
    const float* __restrict__ Wd_neg, const float* __restrict__ bd_neg,
    const int* __restrict__ pos_src, const int* __restrict__ pos_dst,
    const int* __restrict__ neg_src, const int* __restrict__ neg_dst,
    float* __restrict__ emb)
{
    __shared__ float Sx[10][64];        // node features
    __shared__ float Sm[2][10][64];     // base in-means (pos,neg)
    __shared__ float Sagg[6][10][32];   // app_in,app_out,ann_in,ann_out,anp_in,apn_in
    __shared__ float Sh[2][10][32];     // hp, hn
    __shared__ float Shn[2][10][32];    // next hp, hn
    __shared__ int   Ses[4][40];        // pos_src, pos_dst, neg_src, neg_dst (local ids)
    __shared__ int   Scnt[4][10];       // counts over each index array

    const int gid = blockIdx.x;
    const int nb  = gid * PP;
    const int tid = threadIdx.x;

    // load node features
    for (int i = tid; i < 640; i += 64) ((float*)Sx)[i] = x0[nb*64 + i];
    // load edges
    {
        const int* eptr0 = pos_src; const int* eptr1 = pos_dst;
        const int* eptr2 = neg_src; const int* eptr3 = neg_dst;
        for (int i = tid; i < 160; i += 64) {
            int b = i / 40, e = i % 40;
            const int* p = (b==0)?eptr0:(b==1)?eptr1:(b==2)?eptr2:eptr3;
            ((int*)Ses)[i] = p[gid*40 + e];
        }
    }
    __syncthreads();
    // counts
    if (tid < 40) {
        int b = tid / 10, n = tid % 10;
        int cc = 0;
        for (int e = 0; e < 40; ++e) cc += (Ses[b][e] == n);
        Scnt[b][n] = cc;
    }
    for (int i = tid; i < 1280; i += 64) ((float*)Sm)[i] = 0.f;
    __syncthreads();
    // base in-sums: thread owns dim d = tid (0..63)
    {
        const int d = tid;
        for (int e = 0; e < 40; ++e) Sm[0][Ses[0][e]][d] += Sx[Ses[1][e]][d];
        for (int e = 0; e < 40; ++e) Sm[1][Ses[2][e]][d] += Sx[Ses[3][e]][d];
    }
    __syncthreads();
    for (int i = tid; i < 1280; i += 64) {
        int s = i / 640, n = (i % 640) / 64;
        ((float*)Sm)[i] /= fmaxf((float)Scnt[s ? 2 : 0][n], 1.f);
    }
    __syncthreads();

    const int sign = tid >> 5;
    const int g4   = (tid >> 3) & 3;
    const int l8   = tid & 7;
    const int c0   = 4*l8;
    const int kp   = g4*8;

    float acc[10][4];
#pragma unroll
    for (int n=0;n<10;++n) { acc[n][0]=0.f; acc[n][1]=0.f; acc[n][2]=0.f; acc[n][3]=0.f; }

    // ---- base GEMM: feats = [mean_in(64) | x(64)], W (128x32) ----
    {
        const float* Wb = sign ? Wb_neg : Wb_pos;
        const float* fb0 = sign ? &Sm[1][0][0] : &Sm[0][0][0];
#pragma unroll
        for (int blk = 0; blk < 4; ++blk) {
            const float* bp = ((blk < 2) ? fb0 : &Sx[0][0]) + (blk & 1)*32 + kp;
            const float* wrow = Wb + (blk*32 + kp)*32 + c0;
            for (int kk = 0; kk < 8; ++kk) {
                float4 w = *(const float4*)(wrow + kk*32);
#pragma unroll
                for (int n = 0; n < 10; ++n) {
                    float f = bp[n*64 + kk];
                    acc[n][0] += f*w.x; acc[n][1] += f*w.y;
                    acc[n][2] += f*w.z; acc[n][3] += f*w.w;
                }
            }
        }
    }
#pragma unroll
    for (int n=0;n<10;++n)
#pragma unroll
        for (int q=0;q<4;++q) {
            float v = acc[n][q];
            v += __shfl_xor(v, 8);
            v += __shfl_xor(v, 16);
            acc[n][q] = v;
        }
    {
        const float* bb = sign ? bb_neg : bb_pos;
        float4 b4 = *(const float4*)(bb + c0);
#pragma unroll
        for (int n=0;n<10;++n) {
            acc[n][0]+=b4.x; acc[n][1]+=b4.y; acc[n][2]+=b4.z; acc[n][3]+=b4.w;
            float s = acc[n][0]*acc[n][0]+acc[n][1]*acc[n][1]
                    + acc[n][2]*acc[n][2]+acc[n][3]*acc[n][3];
            s += __shfl_xor(s,1); s += __shfl_xor(s,2); s += __shfl_xor(s,4);
            float rn = 1.f / fmaxf(sqrtf(s), 1e-12f);
            if (g4 == 0) {
                Sh[sign][n][c0+0] = acc[n][0]*rn;
                Sh[sign][n][c0+1] = acc[n][1]*rn;
                Sh[sign][n][c0+2] = acc[n][2]*rn;
                Sh[sign][n][c0+3] = acc[n][3]*rn;
            }
        }
    }
    __syncthreads();

    // ---- two deep layers ----
    const int colv = tid & 31;
    for (int l = 0; l < 2; ++l) {
        for (int i = tid; i < 1920; i += 64) ((float*)Sagg)[i] = 0.f;
        __syncthreads();
        {
            const int e0 = 2*sign, e1 = 2*sign + 1;
            const int bA = sign ? 2 : 0;   // in-aggregate (same-sign)
            const int bC = sign ? 5 : 4;   // cross-sign in-aggregate
            for (int e = 0; e < 40; ++e) {
                int sn = Ses[e0][e], dn = Ses[e1][e];
                Sagg[bA][sn][colv] += Sh[sign][dn][colv];
            }
            for (int e = 0; e < 40; ++e) {
                int sn = Ses[e0][e], dn = Ses[e1][e];
                Sagg[bA+1][dn][colv] += Sh[sign][sn][colv];
            }
            for (int e = 0; e < 40; ++e) {
                int sn = Ses[e0][e], dn = Ses[e1][e];
                Sagg[bC][sn][colv] += Sh[1-sign][dn][colv];
            }
        }
        __syncthreads();
        {
            const int cmap0=0,cmap1=1,cmap2=2,cmap3=3,cmap4=0,cmap5=2;
            for (int i = tid; i < 1920; i += 64) {
                int b = i / 320, n = (i % 320) / 32;
                int ci = (b==0)?cmap0:(b==1)?cmap1:(b==2)?cmap2:(b==3)?cmap3:(b==4)?cmap4:cmap5;
                ((float*)Sagg)[i] /= fmaxf((float)Scnt[ci][n], 1.f);
            }
        }
        __syncthreads();
#pragma unroll
        for (int n=0;n<10;++n) { acc[n][0]=0.f; acc[n][1]=0.f; acc[n][2]=0.f; acc[n][3]=0.f; }
        {
            const float* ord[7];
            if (sign == 0) {
                ord[0]=&Sagg[0][0][0]; ord[1]=&Sagg[1][0][0]; ord[2]=&Sagg[2][0][0];
                ord[3]=&Sagg[3][0][0]; ord[4]=&Sagg[4][0][0];
                ord[5]=&Sh[0][0][0];   ord[6]=&Sh[1][0][0];
            } else {
                ord[0]=&Sagg[2][0][0]; ord[1]=&Sagg[3][0][0]; ord[2]=&Sagg[0][0][0];
                ord[3]=&Sagg[1][0][0]; ord[4]=&Sagg[5][0][0];
                ord[5]=&Sh[1][0][0];   ord[6]=&Sh[0][0][0];
            }
            const float* Wd = (sign ? Wd_neg : Wd_pos) + l*7168;
            for (int blk = 0; blk < 7; ++blk) {
                const float* bp = ord[blk] + kp;
                const float* wrow = Wd + (blk*32 + kp)*32 + c0;
                for (int kk = 0; kk < 8; ++kk) {
                    float4 w = *(const float4*)(wrow + kk*32);
#pragma unroll
                    for (int n = 0; n < 10; ++n) {
                        float f = bp[n*32 + kk];
                        acc[n][0] += f*w.x; acc[n][1] += f*w.y;
                        acc[n][2] += f*w.z; acc[n][3] += f*w.w;
                    }
                }
            }
        }
#pragma unroll
        for (int n=0;n<10;++n)
#pragma unroll
            for (int q=0;q<4;++q) {
                float v = acc[n][q];
                v += __shfl_xor(v, 8);
                v += __shfl_xor(v, 16);
                acc[n][q] = v;
            }
        {
            const float* bd = (sign ? bd_neg : bd_pos) + l*32;
            float4 b4 = *(const float4*)(bd + c0);
#pragma unroll
            for (int n=0;n<10;++n) {
                acc[n][0]+=b4.x; acc[n][1]+=b4.y; acc[n][2]+=b4.z; acc[n][3]+=b4.w;
                float s = acc[n][0]*acc[n][0]+acc[n][1]*acc[n][1]
                        + acc[n][2]*acc[n][2]+acc[n][3]*acc[n][3];
                s += __shfl_xor(s,1); s += __shfl_xor(s,2); s += __shfl_xor(s,4);
                float rn = 1.f / fmaxf(sqrtf(s), 1e-12f);
                if (g4 == 0) {
                    Shn[sign][n][c0+0]=acc[n][0]*rn; Shn[sign][n][c0+1]=acc[n][1]*rn;
                    Shn[sign][n][c0+2]=acc[n][2]*rn; Shn[sign][n][c0+3]=acc[n][3]*rn;
                }
            }
        }
        __syncthreads();
        for (int i = tid; i < 640; i += 64) ((float*)Sh)[i] = ((float*)Shn)[i];
        __syncthreads();
    }

    // write emb: [node][0..31]=hp, [32..63]=hn
#pragma unroll
    for (int n = 0; n < 10; ++n) {
        float v = (tid < 32) ? Sh[0][n][tid] : Sh[1][n][tid-32];
        emb[(nb+n)*64 + tid] = v;
    }
}

// ---------------------------------------------------------------------------
// LSTM step: block = 256 threads, 16 rows. Thread owns hidden index j=tid&127
// (all 4 gates via float4 weight loads) and 8 rows. Staged [x|h] in LDS,
// broadcast float4 reads. c/h update fully thread-local.
// ---------------------------------------------------------------------------
__device__ __forceinline__ float sigm(float x) { return 1.f/(1.f+expf(-x)); }

__global__ __launch_bounds__(256) void lstm_step(
    const float* __restrict__ emb, const float* __restrict__ add_info,
    const float* __restrict__ wtih, const float* __restrict__ wthh,
    const float* __restrict__ b_ih, const float* __restrict__ b_hh,
    float* __restrict__ hbuf, float* __restrict__ cbuf, int t)
{
    __shared__ __align__(16) float st[16][200];  // x at [0..65], h at [68..195]
    const int tid = threadIdx.x;
    const int row0 = blockIdx.x * 16;

    for (int i = tid; i < 16*66; i += 256) {
        int r = i / 66, k = i % 66;
        int row = row0 + r;
        int g = row / 10, p = row % 10;
        float v;
        if (k < 64) v = emb[((g*TT + t)*PP + p)*64 + k];
        else        v = add_info[((g*MM + t/5)*PP + p)*2 + (k-64)];
        st[r][k] = v;
    }
    for (int i = tid; i < 16*128; i += 256) {
        int r = i >> 7, k = i & 127;
        st[r][68 + k] = hbuf[(row0 + r)*128 + k];
    }
    __syncthreads();

    const int j  = tid & 127;
    const int r0 = (tid >> 7) * 8;
    float a0[8], a1[8], a2[8], a3[8];
    {
        float bi0 = b_ih[t*512 + j]       + b_hh[t*512 + j];
        float bi1 = b_ih[t*512 + 128 + j] + b_hh[t*512 + 128 + j];
        float bi2 = b_ih[t*512 + 256 + j] + b_hh[t*512 + 256 + j];
        float bi3 = b_ih[t*512 + 384 + j] + b_hh[t*512 + 384 + j];
#pragma unroll
        for (int r=0;r<8;++r){ a0[r]=bi0; a1[r]=bi1; a2[r]=bi2; a3[r]=bi3; }
    }
    const float4* wi4 = (const float4*)(wtih + (size_t)t*66*512);
    const float4* wh4 = (const float4*)(wthh + (size_t)t*128*512);

    // x contribution, k = 0..63 (vectorized) + tail 64,65
    for (int kb = 0; kb < 16; ++kb) {
        float4 f[8];
#pragma unroll
        for (int r=0;r<8;++r) f[r] = *(const float4*)&st[r0+r][4*kb];
#pragma unroll
        for (int kk=0;kk<4;++kk) {
            float4 w = wi4[(4*kb+kk)*128 + j];
#pragma unroll
            for (int r=0;r<8;++r) {
                float fv = (kk==0?f[r].x : kk==1?f[r].y : kk==2?f[r].z : f[r].w);
                a0[r]+=fv*w.x; a1[r]+=fv*w.y; a2[r]+=fv*w.z; a3[r]+=fv*w.w;
            }
        }
    }
#pragma unroll
    for (int k=64;k<66;++k) {
        float4 w = wi4[k*128 + j];
#pragma unroll
        for (int r=0;r<8;++r) {
            float fv = st[r0+r][k];
            a0[r]+=fv*w.x; a1[r]+=fv*w.y; a2[r]+=fv*w.z; a3[r]+=fv*w.w;
        }
    }
    // h contribution, k = 0..127
    for (int kb = 0; kb < 32; ++kb) {
        float4 f[8];
#pragma unroll
        for (int r=0;r<8;++r) f[r] = *(const float4*)&st[r0+r][68+4*kb];
#pragma unroll
        for (int kk=0;kk<4;++kk) {
            float4 w = wh4[(4*kb+kk)*128 + j];
#pragma unroll
            for (int r=0;r<8;++r) {
                float fv = (kk==0?f[r].x : kk==1?f[r].y : kk==2?f[r].z : f[r].w);
                a0[r]+=fv*w.x; a1[r]+=fv*w.y; a2[r]+=fv*w.z; a3[r]+=fv*w.w;
            }
        }
    }
    // gate math + state update
#pragma unroll
    for (int r=0;r<8;++r) {
        int row = row0 + r0 + r;
        float iv = sigm(a0[r]);
        float fv = sigm(a1[r]);
        float gv = tanhf(a2[r]);
        float ov = sigm(a3[r]);
        float cold = cbuf[row*128 + j];
        float cn = fv*cold + iv*gv;
        cbuf[row*128 + j] = cn;
        hbuf[row*128 + j] = ov*tanhf(cn);
    }
}

// ---------------------------------------------------------------------------
// Final projection: out = h_last @ Wf + bf
// ---------------------------------------------------------------------------
__global__ __launch_bounds__(256) void final_proj(
    const float* __restrict__ hbuf, const float* __restrict__ Wf,
    const float* __restrict__ bf, float* __restrict__ out)
{
    __shared__ float wl[128*32];
    __shared__ float hl[64][128];
    const int tid = threadIdx.x;
    const int row0 = blockIdx.x * 64;
    for (int i = tid; i < 4096; i += 256) wl[i] = Wf[i];
    for (int i = tid; i < 8192; i += 256) hl[i>>7][i&127] = hbuf[row0*128 + i];
    __syncthreads();
    const int e  = tid & 31;
    const int rg = tid >> 5;   // 8 groups x 8 rows
    float b = bf[e];
    float acc[8];
#pragma unroll
    for (int r=0;r<8;++r) acc[r] = b;
    for (int k = 0; k < 128; ++k) {
        float w = wl[k*32 + e];
#pragma unroll
        for (int r=0;r<8;++r) acc[r] += hl[rg*8+r][k]*w;
    }
#pragma unroll
    for (int r=0;r<8;++r) out[(row0 + rg*8 + r)*32 + e] = acc[r];
}

// ---------------------------------------------------------------------------
extern "C" void kernel_launch(void* const* d_in, const int* in_sizes, int n_in,
                              void* d_out, int out_size, void* d_ws, size_t ws_size,
                              hipStream_t stream)
{
    const float* x0       = (const float*)d_in[0];
    const float* add_info = (const float*)d_in[1];
    const float* Wb_pos   = (const float*)d_in[2];
    const float* bb_pos   = (const float*)d_in[3];
    const float* Wb_neg   = (const float*)d_in[4];
    const float* bb_neg   = (const float*)d_in[5];
    const float* Wd_pos   = (const float*)d_in[6];
    const float* bd_pos   = (const float*)d_in[7];
    const float* Wd_neg   = (const float*)d_in[8];
    const float* bd_neg   = (const float*)d_in[9];
    const float* W_ih     = (const float*)d_in[10];
    const float* W_hh     = (const float*)d_in[11];
    const float* b_ih     = (const float*)d_in[12];
    const float* b_hh     = (const float*)d_in[13];
    const float* hx0      = (const float*)d_in[14];
    const float* cx0      = (const float*)d_in[15];
    const float* Wf       = (const float*)d_in[16];
    const float* bf       = (const float*)d_in[17];
    const int*   pos_src  = (const int*)d_in[18];
    const int*   pos_dst  = (const int*)d_in[19];
    const int*   neg_src  = (const int*)d_in[20];
    const int*   neg_dst  = (const int*)d_in[21];

    float* ws   = (float*)d_ws;
    float* emb  = ws;                       // 8,192,000 f32
    float* wtih = emb  + 8192000;           //   844,800
    float* wthh = wtih + 844800;            // 1,638,400
    float* hbuf = wthh + 1638400;           //   655,360
    float* cbuf = hbuf + 655360;            //   655,360   (total ~45.7 MiB)

    hipLaunchKernelGGL(prep_kernel, dim3(2048), dim3(256), 0, stream,
                       W_ih, W_hh, hx0, cx0, wtih, wthh, hbuf, cbuf);
    hipLaunchKernelGGL(graph_kernel, dim3(NGRAPH), dim3(64), 0, stream,
                       x0, Wb_pos, bb_pos, Wb_neg, bb_neg,
                       Wd_pos, bd_pos, Wd_neg, bd_neg,
                       pos_src, pos_dst, neg_src, neg_dst, emb);
    for (int t = 0; t < TT; ++t)
        hipLaunchKernelGGL(lstm_step, dim3(320), dim3(256), 0, stream,
                           emb, add_info, wtih, wthh, b_ih, b_hh, hbuf, cbuf, t);
    hipLaunchKernelGGL(final_proj, dim3(80), dim3(256), 0, stream,
                       hbuf, Wf, bf, (float*)d_out);
}

// Round 2
// 1033.496 us; speedup vs baseline: 64.7178x; 64.7178x over previous
//
#include <hip/hip_runtime.h>
#include <math.h>

#define GG 512
#define TT 25
#define PP 10
#define MM 5
#define EE 32
#define HID 32
#define HH 128
#define NEDGE 40
#define NGRAPH (GG*TT)          // 12800
#define NTOT (GG*TT*PP)         // 128000

// ---------------------------------------------------------------------------
// Prep: transpose LSTM weights into [t][k][j][gate] (float4 per (k,j)).
// ---------------------------------------------------------------------------
__global__ void prep_kernel(const float* __restrict__ W_ih, const float* __restrict__ W_hh,
                            float* __restrict__ wtih, float* __restrict__ wthh)
{
    const int N1 = 25*66*512;    // 844800
    const int N2 = 25*128*512;   // 1638400
    const int total = N1 + N2;
    for (int idx = blockIdx.x*blockDim.x + threadIdx.x; idx < total; idx += gridDim.x*blockDim.x) {
        if (idx < N1) {
            int t = idx / (66*512); int rem = idx % (66*512);
            int k = rem / 512; int jc = rem % 512;
            int j = jc >> 2, q = jc & 3;
            wtih[idx] = W_ih[(t*512 + 128*q + j)*66 + k];
        } else {
            int i2 = idx - N1;
            int t = i2 / (128*512); int rem = i2 % (128*512);
            int k = rem / 512; int jc = rem % 512;
            int j = jc >> 2, q = jc & 3;
            wthh[i2] = W_hh[(t*512 + 128*q + j)*128 + k];
        }
    }
}

// ---------------------------------------------------------------------------
// Graph kernel: one 64-thread block per (g,t) vote graph. (unchanged)
// ---------------------------------------------------------------------------
__global__ __launch_bounds__(64) void graph_kernel(
    const float* __restrict__ x0,
    const float* __restrict__ Wb_pos, const float* __restrict__ bb_pos,
    const float* __restrict__ Wb_neg, const float* __restrict__ bb_neg,
    const float* __restrict__ Wd_pos, const float* __restrict__ bd_pos,
    const float* __restrict__ Wd_neg, const float* __restrict__ bd_neg,
    const int* __restrict__ pos_src, const int* __restrict__ pos_dst,
    const int* __restrict__ neg_src, const int* __restrict__ neg_dst,
    float* __restrict__ emb)
{
    __shared__ float Sx[10][64];
    __shared__ float Sm[2][10][64];
    __shared__ float Sagg[6][10][32];
    __shared__ float Sh[2][10][32];
    __shared__ float Shn[2][10][32];
    __shared__ int   Ses[4][40];
    __shared__ int   Scnt[4][10];

    const int gid = blockIdx.x;
    const int nb  = gid * PP;
    const int tid = threadIdx.x;

    for (int i = tid; i < 640; i += 64) ((float*)Sx)[i] = x0[nb*64 + i];
    {
        for (int i = tid; i < 160; i += 64) {
            int b = i / 40, e = i % 40;
            const int* p = (b==0)?pos_src:(b==1)?pos_dst:(b==2)?neg_src:neg_dst;
            ((int*)Ses)[i] = p[gid*40 + e];
        }
    }
    __syncthreads();
    if (tid < 40) {
        int b = tid / 10, n = tid % 10;
        int cc = 0;
        for (int e = 0; e < 40; ++e) cc += (Ses[b][e] == n);
        Scnt[b][n] = cc;
    }
    for (int i = tid; i < 1280; i += 64) ((float*)Sm)[i] = 0.f;
    __syncthreads();
    {
        const int d = tid;
        for (int e = 0; e < 40; ++e) Sm[0][Ses[0][e]][d] += Sx[Ses[1][e]][d];
        for (int e = 0; e < 40; ++e) Sm[1][Ses[2][e]][d] += Sx[Ses[3][e]][d];
    }
    __syncthreads();
    for (int i = tid; i < 1280; i += 64) {
        int s = i / 640, n = (i % 640) / 64;
        ((float*)Sm)[i] /= fmaxf((float)Scnt[s ? 2 : 0][n], 1.f);
    }
    __syncthreads();

    const int sign = tid >> 5;
    const int g4   = (tid >> 3) & 3;
    const int l8   = tid & 7;
    const int c0   = 4*l8;
    const int kp   = g4*8;

    float acc[10][4];
#pragma unroll
    for (int n=0;n<10;++n) { acc[n][0]=0.f; acc[n][1]=0.f; acc[n][2]=0.f; acc[n][3]=0.f; }

    {
        const float* Wb = sign ? Wb_neg : Wb_pos;
        const float* fb0 = sign ? &Sm[1][0][0] : &Sm[0][0][0];
#pragma unroll
        for (int blk = 0; blk < 4; ++blk) {
            const float* bp = ((blk < 2) ? fb0 : &Sx[0][0]) + (blk & 1)*32 + kp;
            const float* wrow = Wb + (blk*32 + kp)*32 + c0;
            for (int kk = 0; kk < 8; ++kk) {
                float4 w = *(const float4*)(wrow + kk*32);
#pragma unroll
                for (int n = 0; n < 10; ++n) {
                    float f = bp[n*64 + kk];
                    acc[n][0] += f*w.x; acc[n][1] += f*w.y;
                    acc[n][2] += f*w.z; acc[n][3] += f*w.w;
                }
            }
        }
    }
#pragma unroll
    for (int n=0;n<10;++n)
#pragma unroll
        for (int q=0;q<4;++q) {
            float v = acc[n][q];
            v += __shfl_xor(v, 8);
            v += __shfl_xor(v, 16);
            acc[n][q] = v;
        }
    {
        const float* bb = sign ? bb_neg : bb_pos;
        float4 b4 = *(const float4*)(bb + c0);
#pragma unroll
        for (int n=0;n<10;++n) {
            acc[n][0]+=b4.x; acc[n][1]+=b4.y; acc[n][2]+=b4.z; acc[n][3]+=b4.w;
            float s = acc[n][0]*acc[n][0]+acc[n][1]*acc[n][1]
                    + acc[n][2]*acc[n][2]+acc[n][3]*acc[n][3];
            s += __shfl_xor(s,1); s += __shfl_xor(s,2); s += __shfl_xor(s,4);
            float rn = 1.f / fmaxf(sqrtf(s), 1e-12f);
            if (g4 == 0) {
                Sh[sign][n][c0+0] = acc[n][0]*rn;
                Sh[sign][n][c0+1] = acc[n][1]*rn;
                Sh[sign][n][c0+2] = acc[n][2]*rn;
                Sh[sign][n][c0+3] = acc[n][3]*rn;
            }
        }
    }
    __syncthreads();

    const int colv = tid & 31;
    for (int l = 0; l < 2; ++l) {
        for (int i = tid; i < 1920; i += 64) ((float*)Sagg)[i] = 0.f;
        __syncthreads();
        {
            const int e0 = 2*sign, e1 = 2*sign + 1;
            const int bA = sign ? 2 : 0;
            const int bC = sign ? 5 : 4;
            for (int e = 0; e < 40; ++e) {
                int sn = Ses[e0][e], dn = Ses[e1][e];
                Sagg[bA][sn][colv] += Sh[sign][dn][colv];
            }
            for (int e = 0; e < 40; ++e) {
                int sn = Ses[e0][e], dn = Ses[e1][e];
                Sagg[bA+1][dn][colv] += Sh[sign][sn][colv];
            }
            for (int e = 0; e < 40; ++e) {
                int sn = Ses[e0][e], dn = Ses[e1][e];
                Sagg[bC][sn][colv] += Sh[1-sign][dn][colv];
            }
        }
        __syncthreads();
        {
            for (int i = tid; i < 1920; i += 64) {
                int b = i / 320, n = (i % 320) / 32;
                int ci = (b==0)?0:(b==1)?1:(b==2)?2:(b==3)?3:(b==4)?0:2;
                ((float*)Sagg)[i] /= fmaxf((float)Scnt[ci][n], 1.f);
            }
        }
        __syncthreads();
#pragma unroll
        for (int n=0;n<10;++n) { acc[n][0]=0.f; acc[n][1]=0.f; acc[n][2]=0.f; acc[n][3]=0.f; }
        {
            const float* ord[7];
            if (sign == 0) {
                ord[0]=&Sagg[0][0][0]; ord[1]=&Sagg[1][0][0]; ord[2]=&Sagg[2][0][0];
                ord[3]=&Sagg[3][0][0]; ord[4]=&Sagg[4][0][0];
                ord[5]=&Sh[0][0][0];   ord[6]=&Sh[1][0][0];
            } else {
                ord[0]=&Sagg[2][0][0]; ord[1]=&Sagg[3][0][0]; ord[2]=&Sagg[0][0][0];
                ord[3]=&Sagg[1][0][0]; ord[4]=&Sagg[5][0][0];
                ord[5]=&Sh[1][0][0];   ord[6]=&Sh[0][0][0];
            }
            const float* Wd = (sign ? Wd_neg : Wd_pos) + l*7168;
            for (int blk = 0; blk < 7; ++blk) {
                const float* bp = ord[blk] + kp;
                const float* wrow = Wd + (blk*32 + kp)*32 + c0;
                for (int kk = 0; kk < 8; ++kk) {
                    float4 w = *(const float4*)(wrow + kk*32);
#pragma unroll
                    for (int n = 0; n < 10; ++n) {
                        float f = bp[n*32 + kk];
                        acc[n][0] += f*w.x; acc[n][1] += f*w.y;
                        acc[n][2] += f*w.z; acc[n][3] += f*w.w;
                    }
                }
            }
        }
#pragma unroll
        for (int n=0;n<10;++n)
#pragma unroll
            for (int q=0;q<4;++q) {
                float v = acc[n][q];
                v += __shfl_xor(v, 8);
                v += __shfl_xor(v, 16);
                acc[n][q] = v;
            }
        {
            const float* bd = (sign ? bd_neg : bd_pos) + l*32;
            float4 b4 = *(const float4*)(bd + c0);
#pragma unroll
            for (int n=0;n<10;++n) {
                acc[n][0]+=b4.x; acc[n][1]+=b4.y; acc[n][2]+=b4.z; acc[n][3]+=b4.w;
                float s = acc[n][0]*acc[n][0]+acc[n][1]*acc[n][1]
                        + acc[n][2]*acc[n][2]+acc[n][3]*acc[n][3];
                s += __shfl_xor(s,1); s += __shfl_xor(s,2); s += __shfl_xor(s,4);
                float rn = 1.f / fmaxf(sqrtf(s), 1e-12f);
                if (g4 == 0) {
                    Shn[sign][n][c0+0]=acc[n][0]*rn; Shn[sign][n][c0+1]=acc[n][1]*rn;
                    Shn[sign][n][c0+2]=acc[n][2]*rn; Shn[sign][n][c0+3]=acc[n][3]*rn;
                }
            }
        }
        __syncthreads();
        for (int i = tid; i < 640; i += 64) ((float*)Sh)[i] = ((float*)Shn)[i];
        __syncthreads();
    }

#pragma unroll
    for (int n = 0; n < 10; ++n) {
        float v = (tid < 32) ? Sh[0][n][tid] : Sh[1][n][tid-32];
        emb[(nb+n)*64 + tid] = v;
    }
}

// ---------------------------------------------------------------------------
// Persistent LSTM: ALL 25 steps in one kernel. 256 blocks x 512 threads.
// Block owns 20 rows (= 2 vote-graph groups of the G*P batch). Thread =
// (j = tid&127, grp = tid>>7) computes rows grp*5..grp*5+4, all 4 gates.
// h in LDS, c in 5 registers. 20 statically-indexed accumulators -> no spill.
// ---------------------------------------------------------------------------
__device__ __forceinline__ float sigm(float x) { return 1.f/(1.f+expf(-x)); }

__global__ __launch_bounds__(512) void lstm_all(
    const float* __restrict__ emb, const float* __restrict__ add_info,
    const float* __restrict__ wtih, const float* __restrict__ wthh,
    const float* __restrict__ b_ih, const float* __restrict__ b_hh,
    const float* __restrict__ hx0, const float* __restrict__ cx0,
    float* __restrict__ hbuf)
{
    __shared__ float Sh[20][128];
    __shared__ float Sx[20][68];
    const int tid  = threadIdx.x;
    const int j    = tid & 127;
    const int grp  = tid >> 7;          // 0..3
    const int row0 = blockIdx.x * 20;   // global row base (row = g*10+p)
    const int r0   = grp * 5;

    // init h -> LDS, c -> regs
    for (int i = tid; i < 20*128; i += 512)
        Sh[i >> 7][i & 127] = hx0[row0*128 + i];
    float c[5];
#pragma unroll
    for (int r = 0; r < 5; ++r)
        c[r] = cx0[(row0 + r0 + r)*128 + j];

    for (int t = 0; t < TT; ++t) {
        // stage x_t: emb is [(g*25+t)*10+p][64]; block rows are g=2b,2b+1
        for (int i = tid; i < 20*64; i += 512) {
            int r = i >> 6, k = i & 63;
            int row = row0 + r;
            int g = row / 10, p = row % 10;
            Sx[r][k] = emb[((g*TT + t)*PP + p)*64 + k];
        }
        if (tid < 40) {
            int r = tid >> 1, k = tid & 1;
            int row = row0 + r;
            int g = row / 10, p = row % 10;
            Sx[r][64 + k] = add_info[((g*MM + t/5)*PP + p)*2 + k];
        }
        __syncthreads();

        float a0[5], a1[5], a2[5], a3[5];
        {
            float bi0 = b_ih[t*512 + j]       + b_hh[t*512 + j];
            float bi1 = b_ih[t*512 + 128 + j] + b_hh[t*512 + 128 + j];
            float bi2 = b_ih[t*512 + 256 + j] + b_hh[t*512 + 256 + j];
            float bi3 = b_ih[t*512 + 384 + j] + b_hh[t*512 + 384 + j];
#pragma unroll
            for (int r = 0; r < 5; ++r) { a0[r]=bi0; a1[r]=bi1; a2[r]=bi2; a3[r]=bi3; }
        }
        const float4* wi = (const float4*)(wtih + (size_t)t*66*512) + j;
        const float4* wh = (const float4*)(wthh + (size_t)t*128*512) + j;

        // x contribution: k = 0..63 in quads, then tail k=64,65
        for (int kb = 0; kb < 16; ++kb) {
            float4 w0 = wi[(4*kb+0)*128];
            float4 w1 = wi[(4*kb+1)*128];
            float4 w2 = wi[(4*kb+2)*128];
            float4 w3 = wi[(4*kb+3)*128];
#pragma unroll
            for (int r = 0; r < 5; ++r) {
                float4 f = *(const float4*)&Sx[r0 + r][4*kb];
                a0[r] += f.x*w0.x + f.y*w1.x + f.z*w2.x + f.w*w3.x;
                a1[r] += f.x*w0.y + f.y*w1.y + f.z*w2.y + f.w*w3.y;
                a2[r] += f.x*w0.z + f.y*w1.z + f.z*w2.z + f.w*w3.z;
                a3[r] += f.x*w0.w + f.y*w1.w + f.z*w2.w + f.w*w3.w;
            }
        }
#pragma unroll
        for (int k = 64; k < 66; ++k) {
            float4 w = wi[k*128];
#pragma unroll
            for (int r = 0; r < 5; ++r) {
                float f = Sx[r0 + r][k];
                a0[r] += f*w.x; a1[r] += f*w.y; a2[r] += f*w.z; a3[r] += f*w.w;
            }
        }
        // h contribution: k = 0..127 in quads
        for (int kb = 0; kb < 32; ++kb) {
            float4 w0 = wh[(4*kb+0)*128];
            float4 w1 = wh[(4*kb+1)*128];
            float4 w2 = wh[(4*kb+2)*128];
            float4 w3 = wh[(4*kb+3)*128];
#pragma unroll
            for (int r = 0; r < 5; ++r) {
                float4 f = *(const float4*)&Sh[r0 + r][4*kb];
                a0[r] += f.x*w0.x + f.y*w1.x + f.z*w2.x + f.w*w3.x;
                a1[r] += f.x*w0.y + f.y*w1.y + f.z*w2.y + f.w*w3.y;
                a2[r] += f.x*w0.z + f.y*w1.z + f.z*w2.z + f.w*w3.z;
                a3[r] += f.x*w0.w + f.y*w1.w + f.z*w2.w + f.w*w3.w;
            }
        }
        __syncthreads();   // all reads of Sh/Sx done before overwrite
        // gate nonlinearities + state update + h write
#pragma unroll
        for (int r = 0; r < 5; ++r) {
            float iv = sigm(a0[r]);
            float fv = sigm(a1[r]);
            float gv = tanhf(a2[r]);
            float ov = sigm(a3[r]);
            float cn = fv*c[r] + iv*gv;
            c[r] = cn;
            float hv = ov*tanhf(cn);
            Sh[r0 + r][j] = hv;
            if (t == TT-1) hbuf[(row0 + r0 + r)*128 + j] = hv;
        }
    }
}

// ---------------------------------------------------------------------------
// Final projection: out = h_last @ Wf + bf
// ---------------------------------------------------------------------------
__global__ __launch_bounds__(256) void final_proj(
    const float* __restrict__ hbuf, const float* __restrict__ Wf,
    const float* __restrict__ bf, float* __restrict__ out)
{
    __shared__ float wl[128*32];
    __shared__ float hl[64][128];
    const int tid = threadIdx.x;
    const int row0 = blockIdx.x * 64;
    for (int i = tid; i < 4096; i += 256) wl[i] = Wf[i];
    for (int i = tid; i < 8192; i += 256) hl[i>>7][i&127] = hbuf[row0*128 + i];
    __syncthreads();
    const int e  = tid & 31;
    const int rg = tid >> 5;
    float b = bf[e];
    float acc[8];
#pragma unroll
    for (int r=0;r<8;++r) acc[r] = b;
    for (int k = 0; k < 128; ++k) {
        float w = wl[k*32 + e];
#pragma unroll
        for (int r=0;r<8;++r) acc[r] += hl[rg*8+r][k]*w;
    }
#pragma unroll
    for (int r=0;r<8;++r) out[(row0 + rg*8 + r)*32 + e] = acc[r];
}

// ---------------------------------------------------------------------------
extern "C" void kernel_launch(void* const* d_in, const int* in_sizes, int n_in,
                              void* d_out, int out_size, void* d_ws, size_t ws_size,
                              hipStream_t stream)
{
    const float* x0       = (const float*)d_in[0];
    const float* add_info = (const float*)d_in[1];
    const float* Wb_pos   = (const float*)d_in[2];
    const float* bb_pos   = (const float*)d_in[3];
    const float* Wb_neg   = (const float*)d_in[4];
    const float* bb_neg   = (const float*)d_in[5];
    const float* Wd_pos   = (const float*)d_in[6];
    const float* bd_pos   = (const float*)d_in[7];
    const float* Wd_neg   = (const float*)d_in[8];
    const float* bd_neg   = (const float*)d_in[9];
    const float* W_ih     = (const float*)d_in[10];
    const float* W_hh     = (const float*)d_in[11];
    const float* b_ih     = (const float*)d_in[12];
    const float* b_hh     = (const float*)d_in[13];
    const float* hx0      = (const float*)d_in[14];
    const float* cx0      = (const float*)d_in[15];
    const float* Wf       = (const float*)d_in[16];
    const float* bf       = (const float*)d_in[17];
    const int*   pos_src  = (const int*)d_in[18];
    const int*   pos_dst  = (const int*)d_in[19];
    const int*   neg_src  = (const int*)d_in[20];
    const int*   neg_dst  = (const int*)d_in[21];

    float* ws   = (float*)d_ws;
    float* emb  = ws;                       // 8,192,000 f32
    float* wtih = emb  + 8192000;           //   844,800
    float* wthh = wtih + 844800;            // 1,638,400
    float* hbuf = wthh + 1638400;           //   655,360

    hipLaunchKernelGGL(prep_kernel, dim3(1024), dim3(256), 0, stream,
                       W_ih, W_hh, wtih, wthh);
    hipLaunchKernelGGL(graph_kernel, dim3(NGRAPH), dim3(64), 0, stream,
                       x0, Wb_pos, bb_pos, Wb_neg, bb_neg,
                       Wd_pos, bd_pos, Wd_neg, bd_neg,
                       pos_src, pos_dst, neg_src, neg_dst, emb);
    hipLaunchKernelGGL(lstm_all, dim3(256), dim3(512), 0, stream,
                       emb, add_info, wtih, wthh, b_ih, b_hh, hx0, cx0, hbuf);
    hipLaunchKernelGGL(final_proj, dim3(80), dim3(256), 0, stream,
                       hbuf, Wf, bf, (float*)d_out);
}